// Round 7
// baseline (669.375 us; speedup 1.0000x reference)
//
#include <hip/hip_runtime.h>
#include <hip/hip_bf16.h>

// Problem dims (fixed by setup_inputs)
#define B_ 4
#define S_ 2048
#define D_ 1024
#define E_ 8
#define F_ 4096
#define C_ 512
#define BE_ (B_*E_)

typedef __attribute__((ext_vector_type(8))) short bf16x8;
typedef __attribute__((ext_vector_type(4))) float f32x4;
typedef unsigned short u16;

#define MFMA16 __builtin_amdgcn_mfma_f32_16x16x32_bf16

// ---------------- workspace layout (bytes) ----------------
static constexpr size_t OFF_AFF  = 0;
static constexpr size_t OFF_IDX  = 262144;
static constexpr size_t OFF_GATE = 327680;
static constexpr size_t OFF_XIN  = 393216;
static constexpr size_t OFF_WT1  = OFF_XIN + (size_t)BE_*C_*D_*2;       // 33947648
static constexpr size_t OFF_WT2  = OFF_WT1 + (size_t)E_*F_*D_*2;        // 101056512
static constexpr size_t OFF_H    = OFF_WT2 + (size_t)E_*D_*F_*2;        // 168165376
static constexpr size_t WS_NEED  = OFF_H   + (size_t)BE_*C_*F_*2;       // ~288 MB

static __device__ __forceinline__ u16 f2bf(float x) {
  __hip_bfloat16 h = __float2bfloat16(x);
  return *reinterpret_cast<u16*>(&h);
}

// tanh-form GELU via one v_exp_f32: v*sigmoid(1.5957691216*(v+0.044715*v^3)).
static __device__ __forceinline__ float gelu_fast(float v) {
  float y = 1.5957691216f * (v + 0.044715f * v * v * v);
  return v / (1.0f + __expf(-y));
}

static __device__ __forceinline__ void gload16(const void* g, void* l) {
  __builtin_amdgcn_global_load_lds(
      (const __attribute__((address_space(1))) unsigned int*)g,
      (__attribute__((address_space(3))) unsigned int*)l, 16, 0, 0);
}

// ---------------- 1. fused: weight transpose+convert (z<16)  ||  router (z>=16) ----
// z<8: w1 expert z (RI=D,RJ=F); 8<=z<16: w2 expert z-8 (RI=F,RJ=D).
// z in {16,17}: router logits+softmax, 4 waves/block, 1 token per wave.
__global__ void trans_router_kernel(const float* __restrict__ w1,
                                    const float* __restrict__ w2,
                                    u16* __restrict__ wt1, u16* __restrict__ wt2,
                                    const float* __restrict__ x,
                                    const float* __restrict__ router,
                                    float* __restrict__ aff) {
  const int z = blockIdx.y;
  const int tid = threadIdx.x;   // 256
  if (z >= 16) {
    // ---- router: token t = ((z-16)*1024 + bid)*4 + wave
    const int wave = tid >> 6, lane = tid & 63;
    const int t = (((z - 16) * 1024) + blockIdx.x) * 4 + wave;  // 0..8191
    const int b = t / S_, s = t % S_;
    const float* xrow = x + (size_t)t * D_;
    float acc[E_];
#pragma unroll
    for (int e = 0; e < E_; ++e) acc[e] = 0.f;
    for (int i = 0; i < D_/64; ++i) {
      int d = lane + i*64;
      float xv = xrow[d];
      const float* r = router + (size_t)d * E_;
#pragma unroll
      for (int e = 0; e < E_; ++e) acc[e] += xv * r[e];
    }
#pragma unroll
    for (int e = 0; e < E_; ++e) {
      float v = acc[e];
      for (int off = 32; off; off >>= 1) v += __shfl_down(v, off);
      acc[e] = v;
    }
    if (lane == 0) {
      float mx = acc[0];
#pragma unroll
      for (int e = 1; e < E_; ++e) mx = fmaxf(mx, acc[e]);
      float ev[E_]; float sum = 0.f;
#pragma unroll
      for (int e = 0; e < E_; ++e) { ev[e] = expf(acc[e] - mx); sum += ev[e]; }
      float inv = 1.0f / sum;
#pragma unroll
      for (int e = 0; e < E_; ++e) aff[((size_t)(b*E_ + e))*S_ + s] = ev[e]*inv;
    }
    return;
  }
  // ---- transpose
  __shared__ float tl[64][65];
  const float* s; u16* d; int RI, RJ, jb, ib;
  if (z < 8) { s = w1 + (size_t)z*D_*F_;     d = wt1 + (size_t)z*D_*F_;
               RI = D_; RJ = F_; jb = blockIdx.x & 63; ib = blockIdx.x >> 6; }
  else       { s = w2 + (size_t)(z-8)*F_*D_; d = wt2 + (size_t)(z-8)*F_*D_;
               RI = F_; RJ = D_; jb = blockIdx.x & 15; ib = blockIdx.x >> 4; }
  const int j0 = jb * 64, i0 = ib * 64;
#pragma unroll
  for (int it = 0; it < 4; ++it) {
    int fid = it*256 + tid;
    int r = fid >> 4, c4 = fid & 15;
    float4 v = *(const float4*)(s + (size_t)(i0 + r) * RJ + j0 + c4*4);
    tl[r][c4*4+0] = v.x; tl[r][c4*4+1] = v.y; tl[r][c4*4+2] = v.z; tl[r][c4*4+3] = v.w;
  }
  __syncthreads();
#pragma unroll
  for (int it = 0; it < 4; ++it) {
    int fid = it*256 + tid;
    int rn = fid >> 4, c4 = fid & 15;
    ushort4 o;
    o.x = f2bf(tl[c4*4+0][rn]); o.y = f2bf(tl[c4*4+1][rn]);
    o.z = f2bf(tl[c4*4+2][rn]); o.w = f2bf(tl[c4*4+3][rn]);
    *(ushort4*)(d + (size_t)(j0 + rn) * RI + i0 + c4*4) = o;
  }
}

// ---------------- 2. top-C select per (b,e): radix-threshold (order-free) ----
__global__ void select_kernel(const float* __restrict__ aff,
                              int* __restrict__ idxb, float* __restrict__ gateb) {
  __shared__ unsigned hist[2048];
  __shared__ unsigned chunk[256];
  __shared__ unsigned scv[2];      // [0]=bin, [1]=remaining need
  __shared__ unsigned cnt, tiecnt;
  const int be = blockIdx.x, tid = threadIdx.x;   // 256 threads
  const int lane = tid & 63, wave = tid >> 6;
  const float* a = aff + (size_t)be * S_;
  unsigned bits[8];
#pragma unroll
  for (int i = 0; i < 8; ++i) bits[i] = __float_as_uint(a[i*256 + tid]);

  unsigned target = C_;
  unsigned tb1, tb2, tb3;

  // ---- pass 1: key = bits[30:20]
  for (int i = tid; i < 2048; i += 256) hist[i] = 0;
  if (tid == 0) { cnt = 0; tiecnt = 0; }
  __syncthreads();
#pragma unroll
  for (int i = 0; i < 8; ++i) atomicAdd(&hist[bits[i] >> 20], 1u);
  __syncthreads();
  {
    unsigned cs = 0;
#pragma unroll
    for (int k = 0; k < 8; ++k) cs += hist[tid*8 + k];
    chunk[tid] = cs;
    __syncthreads();
    if (tid == 0) {
      unsigned cum = 0; int cc = 255;
      while (cum + chunk[cc] < target) { cum += chunk[cc]; --cc; }
      int bb = cc*8 + 7;
      while (cum + hist[bb] < target) { cum += hist[bb]; --bb; }
      scv[0] = (unsigned)bb; scv[1] = target - cum;
    }
    __syncthreads();
    tb1 = scv[0]; target = scv[1];
    __syncthreads();
  }
  // ---- pass 2: among key1==tb1, key = bits[19:9]
  for (int i = tid; i < 2048; i += 256) hist[i] = 0;
  __syncthreads();
#pragma unroll
  for (int i = 0; i < 8; ++i)
    if ((bits[i] >> 20) == tb1) atomicAdd(&hist[(bits[i] >> 9) & 0x7FF], 1u);
  __syncthreads();
  {
    unsigned cs = 0;
#pragma unroll
    for (int k = 0; k < 8; ++k) cs += hist[tid*8 + k];
    chunk[tid] = cs;
    __syncthreads();
    if (tid == 0) {
      unsigned cum = 0; int cc = 255;
      while (cum + chunk[cc] < target) { cum += chunk[cc]; --cc; }
      int bb = cc*8 + 7;
      while (cum + hist[bb] < target) { cum += hist[bb]; --bb; }
      scv[0] = (unsigned)bb; scv[1] = target - cum;
    }
    __syncthreads();
    tb2 = scv[0]; target = scv[1];
    __syncthreads();
  }
  // ---- pass 3: among bits[30:9] == (tb1<<11|tb2), key = bits[8:0]
  const unsigned hi22 = (tb1 << 11) | tb2;
  for (int i = tid; i < 512; i += 256) hist[i] = 0;
  __syncthreads();
#pragma unroll
  for (int i = 0; i < 8; ++i)
    if ((bits[i] >> 9) == hi22) atomicAdd(&hist[bits[i] & 0x1FF], 1u);
  __syncthreads();
  {
    unsigned cs = 0;
    if (tid < 64) {
#pragma unroll
      for (int k = 0; k < 8; ++k) cs += hist[tid*8 + k];
      chunk[tid] = cs;
    }
    __syncthreads();
    if (tid == 0) {
      unsigned cum = 0; int cc = 63;
      while (cum + chunk[cc] < target) { cum += chunk[cc]; --cc; }
      int bb = cc*8 + 7;
      while (cum + hist[bb] < target) { cum += hist[bb]; --bb; }
      scv[0] = (unsigned)bb; scv[1] = target - cum;
    }
    __syncthreads();
    tb3 = scv[0]; target = scv[1];   // target = #ties to take, >=1
  }
  const unsigned T = (tb1 << 20) | (tb2 << 9) | tb3;

  // ---- append all strictly-above-T (any order: combine is additive)
#pragma unroll
  for (int i = 0; i < 8; ++i) {
    if (bits[i] > T) {
      unsigned pos = atomicAdd(&cnt, 1u);
      idxb[be*C_ + pos]  = i*256 + tid;
      gateb[be*C_ + pos] = __uint_as_float(bits[i]);
    }
  }
  __syncthreads();
  const unsigned cnt0 = cnt;        // == C_ - target
  // ---- ties (bits == T): take first `target` by index asc
  for (int rnd = 0; rnd < 8; ++rnd) {
    bool eq = (bits[rnd] == T);
    for (int w = 0; w < 4; ++w) {
      if (wave == w) {
        unsigned long long m = __ballot(eq);
        int below = __popcll(m & ((1ull << lane) - 1ull));
        unsigned base = tiecnt;
        if (eq) {
          unsigned k = base + (unsigned)below;
          if (k < target) {
            unsigned pos = cnt0 + k;
            idxb[be*C_ + pos]  = rnd*256 + tid;
            gateb[be*C_ + pos] = __uint_as_float(bits[rnd]);
          }
        }
        if (lane == 0) tiecnt = base + (unsigned)__popcll(m);
      }
      __syncthreads();
    }
  }
}

// ---------------- 3. gather x rows -> x_in (BE,C,D) bf16 ----------------
__global__ void gather_kernel(const float* __restrict__ x,
                              const int* __restrict__ idxb,
                              u16* __restrict__ x_in) {
  int rid = blockIdx.x;          // be*C + c
  int be = rid >> 9;             // /C_
  int b = be >> 3;               // /E_
  int tok = idxb[rid];
  const float4* src = (const float4*)(x + ((size_t)(b * S_ + tok)) * D_);
  ushort4* dst = (ushort4*)(x_in + (size_t)rid * D_);
  int t = threadIdx.x;           // 128 threads
#pragma unroll
  for (int i = 0; i < 2; ++i) {
    float4 v = src[t + i*128];
    ushort4 o;
    o.x = f2bf(v.x); o.y = f2bf(v.y); o.z = f2bf(v.z); o.w = f2bf(v.w);
    dst[t + i*128] = o;
  }
}

// ---------------- 5a. GEMM1: 2-phase 128x128, (b,mb)-fastest, 5 blocks/CU ----
// h = gelu_fast(x_in @ wt1^T + b1), bf16 out. XCD decode: e = bid&7.
// launch_bounds(256,5): 5 blocks/CU x 32KB LDS = 160KB exactly; VGPR<=102 (uses ~60).
template<int N, int K, int NBLK>
__global__ __launch_bounds__(256, 5)
void gemm1_kernel(const u16* __restrict__ A, const u16* __restrict__ Bt,
                  const float* __restrict__ bias, __hip_bfloat16* __restrict__ outp) {
  __shared__ __align__(16) char lds[32768];   // A tile 16KB | B tile 16KB
  char* ldsA = lds;
  char* ldsB = lds + 16384;
  const int tid  = threadIdx.x;
  const int wave = tid >> 6, lane = tid & 63;

  const int bid = blockIdx.x;
  const int e   = bid & 7;           // XCD id == expert id
  const int r   = bid >> 3;
  const int g   = r & 15;            // (b,mb) fastest: 16 blocks share a B-panel
  const int nb  = r >> 4;
  const int mb  = g & 3;             // C_/128 = 4
  const int b   = g >> 2;            // B_ = 4
  const int be  = b * E_ + e;
  const int m0  = mb * 128;
  const int n0  = nb * 128;

  const u16* Ab = A  + (size_t)be * C_ * K + (size_t)m0 * K;
  const u16* Bb = Bt + (size_t)e  * N  * K + (size_t)n0 * K;

  f32x4 acc[4][4];
#pragma unroll
  for (int i = 0; i < 4; ++i)
#pragma unroll
    for (int j = 0; j < 4; ++j) acc[i][j] = (f32x4){0.f,0.f,0.f,0.f};

  const int wr = wave >> 1, wc = wave & 1;
  const int chi = lane >> 4;    // 0..3
  const int l15 = lane & 15;

  for (int kt = 0; kt < K/64; ++kt) {
    const int k0 = kt * 64;
#pragma unroll
    for (int i = 0; i < 4; ++i) {
      int slot = i*256 + tid;
      int row = slot >> 3, c = slot & 7;
      int sc = (c ^ (row & 7)) << 3;     // source swizzle, bf16 elements
      gload16(Ab + (size_t)row * K + k0 + sc, ldsA + (i*256 + wave*64)*16);
      gload16(Bb + (size_t)row * K + k0 + sc, ldsB + (i*256 + wave*64)*16);
    }
    __syncthreads();
    bf16x8 af[2][4], bfr[2][4];
#pragma unroll
    for (int kk = 0; kk < 2; ++kk) {
#pragma unroll
      for (int mi = 0; mi < 4; ++mi) {
        int row = wr*64 + mi*16 + l15;
        int ch  = kk*4 + chi;
        af[kk][mi] = *(const bf16x8*)(ldsA + row*128 + (((ch ^ (row & 7)) << 4)));
        int rowb = wc*64 + mi*16 + l15;
        bfr[kk][mi] = *(const bf16x8*)(ldsB + rowb*128 + (((ch ^ (rowb & 7)) << 4)));
      }
    }
#pragma unroll
    for (int kk = 0; kk < 2; ++kk)
#pragma unroll
      for (int mi = 0; mi < 4; ++mi)
#pragma unroll
        for (int ni = 0; ni < 4; ++ni)
          acc[mi][ni] = MFMA16(af[kk][mi], bfr[kk][ni], acc[mi][ni], 0, 0, 0);
    __syncthreads();
  }

  const int r4 = lane >> 4;
  __hip_bfloat16* hb = outp + (size_t)be * C_ * N;
  const float* bias_e = bias + e * N;
#pragma unroll
  for (int mi = 0; mi < 4; ++mi) {
#pragma unroll
    for (int j = 0; j < 4; ++j) {
      int row = m0 + wr*64 + mi*16 + r4*4 + j;
      __hip_bfloat16* hrow = hb + (size_t)row * N;
#pragma unroll
      for (int ni = 0; ni < 4; ++ni) {
        int col = n0 + wc*64 + ni*16 + l15;
        float v = acc[mi][ni][j] + bias_e[col];
        hrow[col] = __float2bfloat16(gelu_fast(v));
      }
    }
  }
}

// ---------------- 5b. GEMM2: 256x256 8-phase (measured best at K=4096) ----
// atomic scatter (h @ wt2^T + b2) * gate -> dout. XCD decode: e = bid&7.
template<int N, int K, int NBLK>
__global__ __launch_bounds__(512, 2)
void gemm2_kernel(const u16* __restrict__ A, const u16* __restrict__ Bt,
                  const float* __restrict__ bias,
                  const int* __restrict__ idxb, const float* __restrict__ gateb,
                  float* __restrict__ dout) {
  constexpr int NT = K / 64;
  __shared__ __align__(16) char lds[131072];
  const int tid  = threadIdx.x;
  const int wave = tid >> 6, lane = tid & 63;
  const int wm = wave >> 2, wn = wave & 3;
  const int l15 = lane & 15, chi = lane >> 4;

  const int bid = blockIdx.x;
  const int e   = bid & 7;           // XCD id == expert id
  const int r   = bid >> 3;
  const int nb  = r % NBLK;
  const int rm  = r / NBLK;
  const int mb  = rm & 1;            // C_/256 = 2
  const int b   = rm >> 1;           // B_ = 4
  const int be  = b * E_ + e;
  const int m0  = mb * 256;
  const int n0  = nb * 256;

  const u16* Ab  = A  + (size_t)be * C_ * K + (size_t)m0 * K;
  const u16* Bb  = Bt + (size_t)e  * N  * K + (size_t)n0 * K;
  const u16* Ab2 = Ab + (size_t)128 * K;
  const u16* Bb2 = Bb + (size_t)128 * K;

  const int sr = tid >> 3, scn = tid & 7;
  const size_t off0 = (size_t)sr * K + (size_t)((scn ^ (sr & 7)) << 3);
  const size_t off1 = off0 + (size_t)64 * K;
  const int ldsd = tid * 16;

#define STAGE(tt, so, gb) \
  if ((tt) < NT) { \
    const u16* g_ = (gb) + (size_t)(tt) * 64; \
    char* l_ = lds + (((tt) & 1) * 65536) + (so); \
    gload16(g_ + off0, l_ + ldsd); \
    gload16(g_ + off1, l_ + 8192 + ldsd); \
  }

  const int q7  = l15 & 7;
  const int ch0 = ((chi    ) ^ q7) << 4;
  const int ch1 = ((4 + chi) ^ q7) << 4;
  const int aoff = wm * 16384 + l15 * 128;
  const int boff = 32768 + (wn >> 1) * 16384 + (wn & 1) * 8192 + l15 * 128;

  f32x4 acc[8][4];
#pragma unroll
  for (int i = 0; i < 8; ++i)
#pragma unroll
    for (int j = 0; j < 4; ++j) acc[i][j] = (f32x4){0.f,0.f,0.f,0.f};

  STAGE(0, 0,     Ab);
  STAGE(0, 16384, Ab2);
  STAGE(0, 32768, Bb);
  STAGE(0, 49152, Bb2);
  STAGE(1, 32768, Bb);
  STAGE(1, 49152, Bb2);
  asm volatile("s_waitcnt vmcnt(4)" ::: "memory");
  __builtin_amdgcn_s_barrier();

  bf16x8 af[2][4], bA[2][2], bB[2][2];
  for (int t = 0; t < NT; ++t) {
    const char* cb = lds + (t & 1) * 65536;
    // ---- phase 1: read A(mi0-3) + B(ni0-1); stage (t+1,A0s)
#pragma unroll
    for (int m = 0; m < 4; ++m) {
      af[0][m] = *(const bf16x8*)(cb + aoff + m*2048 + ch0);
      af[1][m] = *(const bf16x8*)(cb + aoff + m*2048 + ch1);
    }
#pragma unroll
    for (int n = 0; n < 2; ++n) {
      bA[0][n] = *(const bf16x8*)(cb + boff + n*2048 + ch0);
      bA[1][n] = *(const bf16x8*)(cb + boff + n*2048 + ch1);
    }
    STAGE(t+1, 0, Ab);
    asm volatile("s_waitcnt lgkmcnt(8)" ::: "memory");
    __builtin_amdgcn_s_barrier();
    asm volatile("s_waitcnt lgkmcnt(0)" ::: "memory");
    __builtin_amdgcn_s_setprio(1);
#pragma unroll
    for (int m = 0; m < 4; ++m)
#pragma unroll
      for (int n = 0; n < 2; ++n) {
        acc[m][n] = MFMA16(af[0][m], bA[0][n], acc[m][n], 0, 0, 0);
        acc[m][n] = MFMA16(af[1][m], bA[1][n], acc[m][n], 0, 0, 0);
      }
    __builtin_amdgcn_s_setprio(0);
    __builtin_amdgcn_s_barrier();
    // ---- phase 2: read B(ni2-3); stage (t+1,A1s)
#pragma unroll
    for (int n = 0; n < 2; ++n) {
      bB[0][n] = *(const bf16x8*)(cb + boff + (2+n)*2048 + ch0);
      bB[1][n] = *(const bf16x8*)(cb + boff + (2+n)*2048 + ch1);
    }
    STAGE(t+1, 16384, Ab2);
    __builtin_amdgcn_s_barrier();
    asm volatile("s_waitcnt lgkmcnt(0)" ::: "memory");
    __builtin_amdgcn_s_setprio(1);
#pragma unroll
    for (int m = 0; m < 4; ++m)
#pragma unroll
      for (int n = 0; n < 2; ++n) {
        acc[m][2+n] = MFMA16(af[0][m], bB[0][n], acc[m][2+n], 0, 0, 0);
        acc[m][2+n] = MFMA16(af[1][m], bB[1][n], acc[m][2+n], 0, 0, 0);
      }
    __builtin_amdgcn_s_setprio(0);
    __builtin_amdgcn_s_barrier();
    // ---- phase 3: read A(mi4-7); stage (t+2,B0s) into cur buf
#pragma unroll
    for (int m = 0; m < 4; ++m) {
      af[0][m] = *(const bf16x8*)(cb + aoff + (4+m)*2048 + ch0);
      af[1][m] = *(const bf16x8*)(cb + aoff + (4+m)*2048 + ch1);
    }
    STAGE(t+2, 32768, Bb);
    __builtin_amdgcn_s_barrier();
    asm volatile("s_waitcnt lgkmcnt(0)" ::: "memory");
    __builtin_amdgcn_s_setprio(1);
#pragma unroll
    for (int m = 0; m < 4; ++m)
#pragma unroll
      for (int n = 0; n < 2; ++n) {
        acc[4+m][2+n] = MFMA16(af[0][m], bB[0][n], acc[4+m][2+n], 0, 0, 0);
        acc[4+m][2+n] = MFMA16(af[1][m], bB[1][n], acc[4+m][2+n], 0, 0, 0);
      }
    __builtin_amdgcn_s_setprio(0);
    __builtin_amdgcn_s_barrier();
    // ---- phase 4: stage (t+2,B1s); K-tile boundary counted vmcnt
    STAGE(t+2, 49152, Bb2);
    if (t < NT-2) {
      asm volatile("s_waitcnt vmcnt(4)" ::: "memory");
    } else if (t == NT-2) {
      asm volatile("s_waitcnt vmcnt(0)" ::: "memory");
    }
    __builtin_amdgcn_s_barrier();
    __builtin_amdgcn_s_setprio(1);
#pragma unroll
    for (int m = 0; m < 4; ++m)
#pragma unroll
      for (int n = 0; n < 2; ++n) {
        acc[4+m][n] = MFMA16(af[0][m], bA[0][n], acc[4+m][n], 0, 0, 0);
        acc[4+m][n] = MFMA16(af[1][m], bA[1][n], acc[4+m][n], 0, 0, 0);
      }
    __builtin_amdgcn_s_setprio(0);
    __builtin_amdgcn_s_barrier();
  }
#undef STAGE

  const int r4 = lane >> 4;
  const float* bias_e = bias + e * N;   // N == D_
  int bb = be >> 3;
#pragma unroll
  for (int mi = 0; mi < 8; ++mi) {
#pragma unroll
    for (int j = 0; j < 4; ++j) {
      int rowl = m0 + wm*128 + mi*16 + r4*4 + j;
      int tok = idxb[be*C_ + rowl];
      float gt = gateb[be*C_ + rowl];
      float* orow = dout + ((size_t)bb * S_ + tok) * (size_t)D_;
#pragma unroll
      for (int ni = 0; ni < 4; ++ni) {
        int col = n0 + wn*64 + ni*16 + l15;
        float v = (acc[mi][ni][j] + bias_e[col]) * gt;
        atomicAdd(orow + col, v);
      }
    }
  }
}

extern "C" void kernel_launch(void* const* d_in, const int* in_sizes, int n_in,
                              void* d_out, int out_size, void* d_ws, size_t ws_size,
                              hipStream_t stream) {
  const float* x      = (const float*)d_in[0];
  const float* router = (const float*)d_in[1];
  const float* w1     = (const float*)d_in[2];
  const float* b1     = (const float*)d_in[3];
  const float* w2     = (const float*)d_in[4];
  const float* b2     = (const float*)d_in[5];
  float* out = (float*)d_out;

  if (ws_size < WS_NEED) return;   // workspace too small: fail visibly

  char* ws = (char*)d_ws;
  float* aff   = (float*)(ws + OFF_AFF);
  int*   idxb  = (int*)(ws + OFF_IDX);
  float* gateb = (float*)(ws + OFF_GATE);
  u16*   x_in  = (u16*)(ws + OFF_XIN);
  u16*   wt1   = (u16*)(ws + OFF_WT1);
  u16*   wt2   = (u16*)(ws + OFF_WT2);
  u16*   h     = (u16*)(ws + OFF_H);

  // transposes (z 0..15) || router (z 16..17) in one launch
  trans_router_kernel<<<dim3(1024, 18), 256, 0, stream>>>(
      w1, w2, wt1, wt2, x, router, aff);
  select_kernel<<<BE_, 256, 0, stream>>>(aff, idxb, gateb);
  gather_kernel<<<BE_*C_, 128, 0, stream>>>(x, idxb, x_in);
  hipMemsetAsync(d_out, 0, (size_t)out_size * sizeof(float), stream);

  // GEMM1: 2-phase 128^2 ; grid = 8 * 32 * 4 * 4 = 4096 blocks, 256 thr
  gemm1_kernel<F_, D_, F_/128><<<E_*(F_/128)*4*B_, 256, 0, stream>>>(
      x_in, wt1, b1, (__hip_bfloat16*)h);
  // GEMM2: 8-phase 256^2 ; grid = 8 * 4 * 2 * 4 = 256 blocks, 512 thr
  gemm2_kernel<D_, F_, D_/256><<<E_*(D_/256)*2*B_, 512, 0, stream>>>(
      h, wt2, b2, idxb, gateb, out);
}

// Round 8
// 456.782 us; speedup vs baseline: 1.4654x; 1.4654x over previous
//
#include <hip/hip_runtime.h>
#include <hip/hip_bf16.h>

// Problem dims (fixed by setup_inputs)
#define B_ 4
#define S_ 2048
#define D_ 1024
#define E_ 8
#define F_ 4096
#define C_ 512
#define BE_ (B_*E_)

typedef __attribute__((ext_vector_type(8))) short bf16x8;
typedef __attribute__((ext_vector_type(4))) float f32x4;
typedef unsigned short u16;

#define MFMA16 __builtin_amdgcn_mfma_f32_16x16x32_bf16

// ---------------- workspace layout (bytes) ----------------
static constexpr size_t OFF_AFF  = 0;
static constexpr size_t OFF_IDX  = 262144;
static constexpr size_t OFF_GATE = 327680;
static constexpr size_t OFF_XIN  = 393216;
static constexpr size_t OFF_WT1  = OFF_XIN + (size_t)BE_*C_*D_*2;       // 33947648
static constexpr size_t OFF_WT2  = OFF_WT1 + (size_t)E_*F_*D_*2;        // 101056512
static constexpr size_t OFF_H    = OFF_WT2 + (size_t)E_*D_*F_*2;        // 168165376
static constexpr size_t WS_NEED  = OFF_H   + (size_t)BE_*C_*F_*2;       // ~288 MB

static __device__ __forceinline__ u16 f2bf(float x) {
  __hip_bfloat16 h = __float2bfloat16(x);
  return *reinterpret_cast<u16*>(&h);
}

// tanh-form GELU via one v_exp_f32: v*sigmoid(1.5957691216*(v+0.044715*v^3)).
static __device__ __forceinline__ float gelu_fast(float v) {
  float y = 1.5957691216f * (v + 0.044715f * v * v * v);
  return v / (1.0f + __expf(-y));
}

static __device__ __forceinline__ void gload16(const void* g, void* l) {
  __builtin_amdgcn_global_load_lds(
      (const __attribute__((address_space(1))) unsigned int*)g,
      (__attribute__((address_space(3))) unsigned int*)l, 16, 0, 0);
}

// ---------------- 1. fused: weight transpose+convert (z<16)  ||  router (z>=16) ----
// z<8: w1 expert z (RI=D,RJ=F); 8<=z<16: w2 expert z-8 (RI=F,RJ=D).
// z in {16,17}: router logits+softmax, 4 waves/block, 1 token per wave.
__global__ void trans_router_kernel(const float* __restrict__ w1,
                                    const float* __restrict__ w2,
                                    u16* __restrict__ wt1, u16* __restrict__ wt2,
                                    const float* __restrict__ x,
                                    const float* __restrict__ router,
                                    float* __restrict__ aff) {
  const int z = blockIdx.y;
  const int tid = threadIdx.x;   // 256
  if (z >= 16) {
    // ---- router: token t = ((z-16)*1024 + bid)*4 + wave
    const int wave = tid >> 6, lane = tid & 63;
    const int t = (((z - 16) * 1024) + blockIdx.x) * 4 + wave;  // 0..8191
    const int b = t / S_, s = t % S_;
    const float* xrow = x + (size_t)t * D_;
    float acc[E_];
#pragma unroll
    for (int e = 0; e < E_; ++e) acc[e] = 0.f;
    for (int i = 0; i < D_/64; ++i) {
      int d = lane + i*64;
      float xv = xrow[d];
      const float* r = router + (size_t)d * E_;
#pragma unroll
      for (int e = 0; e < E_; ++e) acc[e] += xv * r[e];
    }
#pragma unroll
    for (int e = 0; e < E_; ++e) {
      float v = acc[e];
      for (int off = 32; off; off >>= 1) v += __shfl_down(v, off);
      acc[e] = v;
    }
    if (lane == 0) {
      float mx = acc[0];
#pragma unroll
      for (int e = 1; e < E_; ++e) mx = fmaxf(mx, acc[e]);
      float ev[E_]; float sum = 0.f;
#pragma unroll
      for (int e = 0; e < E_; ++e) { ev[e] = expf(acc[e] - mx); sum += ev[e]; }
      float inv = 1.0f / sum;
#pragma unroll
      for (int e = 0; e < E_; ++e) aff[((size_t)(b*E_ + e))*S_ + s] = ev[e]*inv;
    }
    return;
  }
  // ---- transpose
  __shared__ float tl[64][65];
  const float* s; u16* d; int RI, RJ, jb, ib;
  if (z < 8) { s = w1 + (size_t)z*D_*F_;     d = wt1 + (size_t)z*D_*F_;
               RI = D_; RJ = F_; jb = blockIdx.x & 63; ib = blockIdx.x >> 6; }
  else       { s = w2 + (size_t)(z-8)*F_*D_; d = wt2 + (size_t)(z-8)*F_*D_;
               RI = F_; RJ = D_; jb = blockIdx.x & 15; ib = blockIdx.x >> 4; }
  const int j0 = jb * 64, i0 = ib * 64;
#pragma unroll
  for (int it = 0; it < 4; ++it) {
    int fid = it*256 + tid;
    int r = fid >> 4, c4 = fid & 15;
    float4 v = *(const float4*)(s + (size_t)(i0 + r) * RJ + j0 + c4*4);
    tl[r][c4*4+0] = v.x; tl[r][c4*4+1] = v.y; tl[r][c4*4+2] = v.z; tl[r][c4*4+3] = v.w;
  }
  __syncthreads();
#pragma unroll
  for (int it = 0; it < 4; ++it) {
    int fid = it*256 + tid;
    int rn = fid >> 4, c4 = fid & 15;
    ushort4 o;
    o.x = f2bf(tl[c4*4+0][rn]); o.y = f2bf(tl[c4*4+1][rn]);
    o.z = f2bf(tl[c4*4+2][rn]); o.w = f2bf(tl[c4*4+3][rn]);
    *(ushort4*)(d + (size_t)(j0 + rn) * RI + i0 + c4*4) = o;
  }
}

// ---------------- 2. top-C select per (b,e): radix-threshold (order-free) ----
__global__ void select_kernel(const float* __restrict__ aff,
                              int* __restrict__ idxb, float* __restrict__ gateb) {
  __shared__ unsigned hist[2048];
  __shared__ unsigned chunk[256];
  __shared__ unsigned scv[2];      // [0]=bin, [1]=remaining need
  __shared__ unsigned cnt, tiecnt;
  const int be = blockIdx.x, tid = threadIdx.x;   // 256 threads
  const int lane = tid & 63, wave = tid >> 6;
  const float* a = aff + (size_t)be * S_;
  unsigned bits[8];
#pragma unroll
  for (int i = 0; i < 8; ++i) bits[i] = __float_as_uint(a[i*256 + tid]);

  unsigned target = C_;
  unsigned tb1, tb2, tb3;

  // ---- pass 1: key = bits[30:20]
  for (int i = tid; i < 2048; i += 256) hist[i] = 0;
  if (tid == 0) { cnt = 0; tiecnt = 0; }
  __syncthreads();
#pragma unroll
  for (int i = 0; i < 8; ++i) atomicAdd(&hist[bits[i] >> 20], 1u);
  __syncthreads();
  {
    unsigned cs = 0;
#pragma unroll
    for (int k = 0; k < 8; ++k) cs += hist[tid*8 + k];
    chunk[tid] = cs;
    __syncthreads();
    if (tid == 0) {
      unsigned cum = 0; int cc = 255;
      while (cum + chunk[cc] < target) { cum += chunk[cc]; --cc; }
      int bb = cc*8 + 7;
      while (cum + hist[bb] < target) { cum += hist[bb]; --bb; }
      scv[0] = (unsigned)bb; scv[1] = target - cum;
    }
    __syncthreads();
    tb1 = scv[0]; target = scv[1];
    __syncthreads();
  }
  // ---- pass 2: among key1==tb1, key = bits[19:9]
  for (int i = tid; i < 2048; i += 256) hist[i] = 0;
  __syncthreads();
#pragma unroll
  for (int i = 0; i < 8; ++i)
    if ((bits[i] >> 20) == tb1) atomicAdd(&hist[(bits[i] >> 9) & 0x7FF], 1u);
  __syncthreads();
  {
    unsigned cs = 0;
#pragma unroll
    for (int k = 0; k < 8; ++k) cs += hist[tid*8 + k];
    chunk[tid] = cs;
    __syncthreads();
    if (tid == 0) {
      unsigned cum = 0; int cc = 255;
      while (cum + chunk[cc] < target) { cum += chunk[cc]; --cc; }
      int bb = cc*8 + 7;
      while (cum + hist[bb] < target) { cum += hist[bb]; --bb; }
      scv[0] = (unsigned)bb; scv[1] = target - cum;
    }
    __syncthreads();
    tb2 = scv[0]; target = scv[1];
    __syncthreads();
  }
  // ---- pass 3: among bits[30:9] == (tb1<<11|tb2), key = bits[8:0]
  const unsigned hi22 = (tb1 << 11) | tb2;
  for (int i = tid; i < 512; i += 256) hist[i] = 0;
  __syncthreads();
#pragma unroll
  for (int i = 0; i < 8; ++i)
    if ((bits[i] >> 9) == hi22) atomicAdd(&hist[bits[i] & 0x1FF], 1u);
  __syncthreads();
  {
    unsigned cs = 0;
    if (tid < 64) {
#pragma unroll
      for (int k = 0; k < 8; ++k) cs += hist[tid*8 + k];
      chunk[tid] = cs;
    }
    __syncthreads();
    if (tid == 0) {
      unsigned cum = 0; int cc = 63;
      while (cum + chunk[cc] < target) { cum += chunk[cc]; --cc; }
      int bb = cc*8 + 7;
      while (cum + hist[bb] < target) { cum += hist[bb]; --bb; }
      scv[0] = (unsigned)bb; scv[1] = target - cum;
    }
    __syncthreads();
    tb3 = scv[0]; target = scv[1];   // target = #ties to take, >=1
  }
  const unsigned T = (tb1 << 20) | (tb2 << 9) | tb3;

  // ---- append all strictly-above-T (any order: combine is additive)
#pragma unroll
  for (int i = 0; i < 8; ++i) {
    if (bits[i] > T) {
      unsigned pos = atomicAdd(&cnt, 1u);
      idxb[be*C_ + pos]  = i*256 + tid;
      gateb[be*C_ + pos] = __uint_as_float(bits[i]);
    }
  }
  __syncthreads();
  const unsigned cnt0 = cnt;        // == C_ - target
  // ---- ties (bits == T): take first `target` by index asc
  for (int rnd = 0; rnd < 8; ++rnd) {
    bool eq = (bits[rnd] == T);
    for (int w = 0; w < 4; ++w) {
      if (wave == w) {
        unsigned long long m = __ballot(eq);
        int below = __popcll(m & ((1ull << lane) - 1ull));
        unsigned base = tiecnt;
        if (eq) {
          unsigned k = base + (unsigned)below;
          if (k < target) {
            unsigned pos = cnt0 + k;
            idxb[be*C_ + pos]  = rnd*256 + tid;
            gateb[be*C_ + pos] = __uint_as_float(bits[rnd]);
          }
        }
        if (lane == 0) tiecnt = base + (unsigned)__popcll(m);
      }
      __syncthreads();
    }
  }
}

// ---------------- 3. gather x rows -> x_in (BE,C,D) bf16 ----------------
__global__ void gather_kernel(const float* __restrict__ x,
                              const int* __restrict__ idxb,
                              u16* __restrict__ x_in) {
  int rid = blockIdx.x;          // be*C + c
  int be = rid >> 9;             // /C_
  int b = be >> 3;               // /E_
  int tok = idxb[rid];
  const float4* src = (const float4*)(x + ((size_t)(b * S_ + tok)) * D_);
  ushort4* dst = (ushort4*)(x_in + (size_t)rid * D_);
  int t = threadIdx.x;           // 128 threads
#pragma unroll
  for (int i = 0; i < 2; ++i) {
    float4 v = src[t + i*128];
    ushort4 o;
    o.x = f2bf(v.x); o.y = f2bf(v.y); o.z = f2bf(v.z); o.w = f2bf(v.w);
    dst[t + i*128] = o;
  }
}

// ---------------- 5a. GEMM1: 2-phase 128x128, (b,mb)-fastest, (256,4) ----
// h = gelu_fast(x_in @ wt1^T + b1), bf16 out. XCD decode: e = bid&7.
// launch_bounds(256,4) is the measured optimum: VGPR=60, 4 blocks/CU, 172us.
// (256,5) spills (VGPR 48, +300MB scratch writes, 400us); (256,3) regresses too.
template<int N, int K, int NBLK>
__global__ __launch_bounds__(256, 4)
void gemm1_kernel(const u16* __restrict__ A, const u16* __restrict__ Bt,
                  const float* __restrict__ bias, __hip_bfloat16* __restrict__ outp) {
  __shared__ __align__(16) char lds[32768];   // A tile 16KB | B tile 16KB
  char* ldsA = lds;
  char* ldsB = lds + 16384;
  const int tid  = threadIdx.x;
  const int wave = tid >> 6, lane = tid & 63;

  const int bid = blockIdx.x;
  const int e   = bid & 7;           // XCD id == expert id
  const int r   = bid >> 3;
  const int g   = r & 15;            // (b,mb) fastest: 16 blocks share a B-panel
  const int nb  = r >> 4;
  const int mb  = g & 3;             // C_/128 = 4
  const int b   = g >> 2;            // B_ = 4
  const int be  = b * E_ + e;
  const int m0  = mb * 128;
  const int n0  = nb * 128;

  const u16* Ab = A  + (size_t)be * C_ * K + (size_t)m0 * K;
  const u16* Bb = Bt + (size_t)e  * N  * K + (size_t)n0 * K;

  f32x4 acc[4][4];
#pragma unroll
  for (int i = 0; i < 4; ++i)
#pragma unroll
    for (int j = 0; j < 4; ++j) acc[i][j] = (f32x4){0.f,0.f,0.f,0.f};

  const int wr = wave >> 1, wc = wave & 1;
  const int chi = lane >> 4;    // 0..3
  const int l15 = lane & 15;

  for (int kt = 0; kt < K/64; ++kt) {
    const int k0 = kt * 64;
#pragma unroll
    for (int i = 0; i < 4; ++i) {
      int slot = i*256 + tid;
      int row = slot >> 3, c = slot & 7;
      int sc = (c ^ (row & 7)) << 3;     // source swizzle, bf16 elements
      gload16(Ab + (size_t)row * K + k0 + sc, ldsA + (i*256 + wave*64)*16);
      gload16(Bb + (size_t)row * K + k0 + sc, ldsB + (i*256 + wave*64)*16);
    }
    __syncthreads();
    bf16x8 af[2][4], bfr[2][4];
#pragma unroll
    for (int kk = 0; kk < 2; ++kk) {
#pragma unroll
      for (int mi = 0; mi < 4; ++mi) {
        int row = wr*64 + mi*16 + l15;
        int ch  = kk*4 + chi;
        af[kk][mi] = *(const bf16x8*)(ldsA + row*128 + (((ch ^ (row & 7)) << 4)));
        int rowb = wc*64 + mi*16 + l15;
        bfr[kk][mi] = *(const bf16x8*)(ldsB + rowb*128 + (((ch ^ (rowb & 7)) << 4)));
      }
    }
#pragma unroll
    for (int kk = 0; kk < 2; ++kk)
#pragma unroll
      for (int mi = 0; mi < 4; ++mi)
#pragma unroll
        for (int ni = 0; ni < 4; ++ni)
          acc[mi][ni] = MFMA16(af[kk][mi], bfr[kk][ni], acc[mi][ni], 0, 0, 0);
    __syncthreads();
  }

  const int r4 = lane >> 4;
  __hip_bfloat16* hb = outp + (size_t)be * C_ * N;
  const float* bias_e = bias + e * N;
#pragma unroll
  for (int mi = 0; mi < 4; ++mi) {
#pragma unroll
    for (int j = 0; j < 4; ++j) {
      int row = m0 + wr*64 + mi*16 + r4*4 + j;
      __hip_bfloat16* hrow = hb + (size_t)row * N;
#pragma unroll
      for (int ni = 0; ni < 4; ++ni) {
        int col = n0 + wc*64 + ni*16 + l15;
        float v = acc[mi][ni][j] + bias_e[col];
        hrow[col] = __float2bfloat16(gelu_fast(v));
      }
    }
  }
}

// ---------------- 5b. GEMM2: 256x256 8-phase (measured best at K=4096) ----
// atomic scatter (h @ wt2^T + b2) * gate -> dout. XCD decode: e = bid&7.
template<int N, int K, int NBLK>
__global__ __launch_bounds__(512, 2)
void gemm2_kernel(const u16* __restrict__ A, const u16* __restrict__ Bt,
                  const float* __restrict__ bias,
                  const int* __restrict__ idxb, const float* __restrict__ gateb,
                  float* __restrict__ dout) {
  constexpr int NT = K / 64;
  __shared__ __align__(16) char lds[131072];
  const int tid  = threadIdx.x;
  const int wave = tid >> 6, lane = tid & 63;
  const int wm = wave >> 2, wn = wave & 3;
  const int l15 = lane & 15, chi = lane >> 4;

  const int bid = blockIdx.x;
  const int e   = bid & 7;           // XCD id == expert id
  const int r   = bid >> 3;
  const int nb  = r % NBLK;
  const int rm  = r / NBLK;
  const int mb  = rm & 1;            // C_/256 = 2
  const int b   = rm >> 1;           // B_ = 4
  const int be  = b * E_ + e;
  const int m0  = mb * 256;
  const int n0  = nb * 256;

  const u16* Ab  = A  + (size_t)be * C_ * K + (size_t)m0 * K;
  const u16* Bb  = Bt + (size_t)e  * N  * K + (size_t)n0 * K;
  const u16* Ab2 = Ab + (size_t)128 * K;
  const u16* Bb2 = Bb + (size_t)128 * K;

  const int sr = tid >> 3, scn = tid & 7;
  const size_t off0 = (size_t)sr * K + (size_t)((scn ^ (sr & 7)) << 3);
  const size_t off1 = off0 + (size_t)64 * K;
  const int ldsd = tid * 16;

#define STAGE(tt, so, gb) \
  if ((tt) < NT) { \
    const u16* g_ = (gb) + (size_t)(tt) * 64; \
    char* l_ = lds + (((tt) & 1) * 65536) + (so); \
    gload16(g_ + off0, l_ + ldsd); \
    gload16(g_ + off1, l_ + 8192 + ldsd); \
  }

  const int q7  = l15 & 7;
  const int ch0 = ((chi    ) ^ q7) << 4;
  const int ch1 = ((4 + chi) ^ q7) << 4;
  const int aoff = wm * 16384 + l15 * 128;
  const int boff = 32768 + (wn >> 1) * 16384 + (wn & 1) * 8192 + l15 * 128;

  f32x4 acc[8][4];
#pragma unroll
  for (int i = 0; i < 8; ++i)
#pragma unroll
    for (int j = 0; j < 4; ++j) acc[i][j] = (f32x4){0.f,0.f,0.f,0.f};

  STAGE(0, 0,     Ab);
  STAGE(0, 16384, Ab2);
  STAGE(0, 32768, Bb);
  STAGE(0, 49152, Bb2);
  STAGE(1, 32768, Bb);
  STAGE(1, 49152, Bb2);
  asm volatile("s_waitcnt vmcnt(4)" ::: "memory");
  __builtin_amdgcn_s_barrier();

  bf16x8 af[2][4], bA[2][2], bB[2][2];
  for (int t = 0; t < NT; ++t) {
    const char* cb = lds + (t & 1) * 65536;
    // ---- phase 1: read A(mi0-3) + B(ni0-1); stage (t+1,A0s)
#pragma unroll
    for (int m = 0; m < 4; ++m) {
      af[0][m] = *(const bf16x8*)(cb + aoff + m*2048 + ch0);
      af[1][m] = *(const bf16x8*)(cb + aoff + m*2048 + ch1);
    }
#pragma unroll
    for (int n = 0; n < 2; ++n) {
      bA[0][n] = *(const bf16x8*)(cb + boff + n*2048 + ch0);
      bA[1][n] = *(const bf16x8*)(cb + boff + n*2048 + ch1);
    }
    STAGE(t+1, 0, Ab);
    asm volatile("s_waitcnt lgkmcnt(8)" ::: "memory");
    __builtin_amdgcn_s_barrier();
    asm volatile("s_waitcnt lgkmcnt(0)" ::: "memory");
    __builtin_amdgcn_s_setprio(1);
#pragma unroll
    for (int m = 0; m < 4; ++m)
#pragma unroll
      for (int n = 0; n < 2; ++n) {
        acc[m][n] = MFMA16(af[0][m], bA[0][n], acc[m][n], 0, 0, 0);
        acc[m][n] = MFMA16(af[1][m], bA[1][n], acc[m][n], 0, 0, 0);
      }
    __builtin_amdgcn_s_setprio(0);
    __builtin_amdgcn_s_barrier();
    // ---- phase 2: read B(ni2-3); stage (t+1,A1s)
#pragma unroll
    for (int n = 0; n < 2; ++n) {
      bB[0][n] = *(const bf16x8*)(cb + boff + (2+n)*2048 + ch0);
      bB[1][n] = *(const bf16x8*)(cb + boff + (2+n)*2048 + ch1);
    }
    STAGE(t+1, 16384, Ab2);
    __builtin_amdgcn_s_barrier();
    asm volatile("s_waitcnt lgkmcnt(0)" ::: "memory");
    __builtin_amdgcn_s_setprio(1);
#pragma unroll
    for (int m = 0; m < 4; ++m)
#pragma unroll
      for (int n = 0; n < 2; ++n) {
        acc[m][2+n] = MFMA16(af[0][m], bB[0][n], acc[m][2+n], 0, 0, 0);
        acc[m][2+n] = MFMA16(af[1][m], bB[1][n], acc[m][2+n], 0, 0, 0);
      }
    __builtin_amdgcn_s_setprio(0);
    __builtin_amdgcn_s_barrier();
    // ---- phase 3: read A(mi4-7); stage (t+2,B0s) into cur buf
#pragma unroll
    for (int m = 0; m < 4; ++m) {
      af[0][m] = *(const bf16x8*)(cb + aoff + (4+m)*2048 + ch0);
      af[1][m] = *(const bf16x8*)(cb + aoff + (4+m)*2048 + ch1);
    }
    STAGE(t+2, 32768, Bb);
    __builtin_amdgcn_s_barrier();
    asm volatile("s_waitcnt lgkmcnt(0)" ::: "memory");
    __builtin_amdgcn_s_setprio(1);
#pragma unroll
    for (int m = 0; m < 4; ++m)
#pragma unroll
      for (int n = 0; n < 2; ++n) {
        acc[4+m][2+n] = MFMA16(af[0][m], bB[0][n], acc[4+m][2+n], 0, 0, 0);
        acc[4+m][2+n] = MFMA16(af[1][m], bB[1][n], acc[4+m][2+n], 0, 0, 0);
      }
    __builtin_amdgcn_s_setprio(0);
    __builtin_amdgcn_s_barrier();
    // ---- phase 4: stage (t+2,B1s); K-tile boundary counted vmcnt
    STAGE(t+2, 49152, Bb2);
    if (t < NT-2) {
      asm volatile("s_waitcnt vmcnt(4)" ::: "memory");
    } else if (t == NT-2) {
      asm volatile("s_waitcnt vmcnt(0)" ::: "memory");
    }
    __builtin_amdgcn_s_barrier();
    __builtin_amdgcn_s_setprio(1);
#pragma unroll
    for (int m = 0; m < 4; ++m)
#pragma unroll
      for (int n = 0; n < 2; ++n) {
        acc[4+m][n] = MFMA16(af[0][m], bA[0][n], acc[4+m][n], 0, 0, 0);
        acc[4+m][n] = MFMA16(af[1][m], bA[1][n], acc[4+m][n], 0, 0, 0);
      }
    __builtin_amdgcn_s_setprio(0);
    __builtin_amdgcn_s_barrier();
  }
#undef STAGE

  const int r4 = lane >> 4;
  const float* bias_e = bias + e * N;   // N == D_
  int bb = be >> 3;
#pragma unroll
  for (int mi = 0; mi < 8; ++mi) {
#pragma unroll
    for (int j = 0; j < 4; ++j) {
      int rowl = m0 + wm*128 + mi*16 + r4*4 + j;
      int tok = idxb[be*C_ + rowl];
      float gt = gateb[be*C_ + rowl];
      float* orow = dout + ((size_t)bb * S_ + tok) * (size_t)D_;
#pragma unroll
      for (int ni = 0; ni < 4; ++ni) {
        int col = n0 + wn*64 + ni*16 + l15;
        float v = (acc[mi][ni][j] + bias_e[col]) * gt;
        atomicAdd(orow + col, v);
      }
    }
  }
}

extern "C" void kernel_launch(void* const* d_in, const int* in_sizes, int n_in,
                              void* d_out, int out_size, void* d_ws, size_t ws_size,
                              hipStream_t stream) {
  const float* x      = (const float*)d_in[0];
  const float* router = (const float*)d_in[1];
  const float* w1     = (const float*)d_in[2];
  const float* b1     = (const float*)d_in[3];
  const float* w2     = (const float*)d_in[4];
  const float* b2     = (const float*)d_in[5];
  float* out = (float*)d_out;

  if (ws_size < WS_NEED) return;   // workspace too small: fail visibly

  char* ws = (char*)d_ws;
  float* aff   = (float*)(ws + OFF_AFF);
  int*   idxb  = (int*)(ws + OFF_IDX);
  float* gateb = (float*)(ws + OFF_GATE);
  u16*   x_in  = (u16*)(ws + OFF_XIN);
  u16*   wt1   = (u16*)(ws + OFF_WT1);
  u16*   wt2   = (u16*)(ws + OFF_WT2);
  u16*   h     = (u16*)(ws + OFF_H);

  // transposes (z 0..15) || router (z 16..17) in one launch
  trans_router_kernel<<<dim3(1024, 18), 256, 0, stream>>>(
      w1, w2, wt1, wt2, x, router, aff);
  select_kernel<<<BE_, 256, 0, stream>>>(aff, idxb, gateb);
  gather_kernel<<<BE_*C_, 128, 0, stream>>>(x, idxb, x_in);
  hipMemsetAsync(d_out, 0, (size_t)out_size * sizeof(float), stream);

  // GEMM1: 2-phase 128^2 ; grid = 8 * 32 * 4 * 4 = 4096 blocks, 256 thr
  gemm1_kernel<F_, D_, F_/128><<<E_*(F_/128)*4*B_, 256, 0, stream>>>(
      x_in, wt1, b1, (__hip_bfloat16*)h);
  // GEMM2: 8-phase 256^2 ; grid = 8 * 4 * 2 * 4 = 256 blocks, 512 thr
  gemm2_kernel<D_, F_, D_/256><<<E_*(D_/256)*2*B_, 512, 0, stream>>>(
      h, wt2, b2, idxb, gateb, out);
}